// Round 7
// baseline (53.844 us; speedup 1.0000x reference)
//
#include <hip/hip_runtime.h>
#include <hip/hip_bf16.h>

typedef __attribute__((ext_vector_type(8))) short short8;
typedef __attribute__((ext_vector_type(4))) float f32x4;

#define NQ 32      // queries
#define NM 32      // query tokens
#define NH 128     // head dim
#define ND 512     // docs
#define NN 180     // doc tokens
#define NNP 192    // padded doc tokens (12 tiles of 16)
#define LSTR 136   // LDS row stride in shorts (272 B)

static __device__ __forceinline__ unsigned short f2bf(float x) {
  __hip_bfloat16 h = __float2bfloat16(x);
  return __builtin_bit_cast(unsigned short, h);
}

// Qb = bf16(Q * q_mask), [32*32][128]
__global__ __launch_bounds__(256, 1) void prep_q_kernel(
    const float* __restrict__ Q, const int* __restrict__ qmask,
    unsigned short* __restrict__ Qb) {
  int idx = blockIdx.x * 256 + threadIdx.x;   // float4 index, 32768 total
  int row = idx >> 5;                          // qm row (32 float4 per row)
  float m = (float)qmask[row];
  float4 v = reinterpret_cast<const float4*>(Q)[idx];
  unsigned int lo = (unsigned)f2bf(v.x * m) | ((unsigned)f2bf(v.y * m) << 16);
  unsigned int hi = (unsigned)f2bf(v.z * m) | ((unsigned)f2bf(v.w * m) << 16);
  reinterpret_cast<uint2*>(Qb)[idx] = make_uint2(lo, hi);
}

static __device__ __forceinline__ f32x4 max4(f32x4 a, f32x4 b) {
  f32x4 r;
  r[0] = fmaxf(a[0], b[0]); r[1] = fmaxf(a[1], b[1]);
  r[2] = fmaxf(a[2], b[2]); r[3] = fmaxf(a[3], b[3]);
  return r;
}

// one workgroup per doc d; 4 waves; wave w owns queries w*8..w*8+7, processed in
// QUADS (4 queries share every Da ds_read -> LDS-pipe demand halved vs pairs:
// 96 ds_read_b128/wave instead of 192; LDS was the dominant non-MFMA consumer).
// Quad loop is a RUNTIME loop (#pragma unroll 1): one quad's working set
// (Qf 128 + Da 16 + acc 32 + run 32 ~ 235 VGPR) live at a time; NO VGPR cap
// (occupancy is grid-limited at 2 blocks/CU -> 2 waves/SIMD regardless).
// Operands swapped: C[n,m] = mfma(Dfrag, Qfrag); max-over-n = j-fold + xor16/32.
__global__ __launch_bounds__(256) void maxsim_kernel(
    const float* __restrict__ D, const int* __restrict__ dmask,
    const unsigned short* __restrict__ Qb, float* __restrict__ out) {
  __shared__ unsigned short Dlds[NNP * LSTR];  // 52224 B
  const int d = blockIdx.x;
  const int tid = threadIdx.x;
  const int lane = tid & 63;
  const int w = tid >> 6;
  const float NEG = -__builtin_inff();

  // ---- stage masked D -> LDS bf16; grouped x4 so 4 loads are in flight ----
  const float4* Dsrc = reinterpret_cast<const float4*>(D) + d * (NN * NH / 4);
  const int* dmrow = dmask + d * NN;
  #pragma unroll 1
  for (int it = 0; it < 5; ++it) {              // 5 x 1024 = 5120 float4s
    int i0 = it * 1024 + tid;
    float4 v[4]; float m[4]; int row[4], c4[4];
    #pragma unroll
    for (int u = 0; u < 4; ++u) {
      int i = i0 + u * 256;
      row[u] = i >> 5; c4[u] = i & 31;
      v[u] = Dsrc[i];
      m[u] = (float)dmrow[row[u]];
    }
    #pragma unroll
    for (int u = 0; u < 4; ++u) {
      unsigned int lo = (unsigned)f2bf(v[u].x * m[u]) | ((unsigned)f2bf(v[u].y * m[u]) << 16);
      unsigned int hi = (unsigned)f2bf(v[u].z * m[u]) | ((unsigned)f2bf(v[u].w * m[u]) << 16);
      *reinterpret_cast<uint2*>(&Dlds[row[u] * LSTR + c4[u] * 4]) = make_uint2(lo, hi);
    }
  }
  for (int i = 5120 + tid; i < NN * (NH / 4); i += 256) {   // tail 640 float4s
    int row = i >> 5, c4 = i & 31;
    float m = (float)dmrow[row];
    float4 v = Dsrc[i];
    unsigned int lo = (unsigned)f2bf(v.x * m) | ((unsigned)f2bf(v.y * m) << 16);
    unsigned int hi = (unsigned)f2bf(v.z * m) | ((unsigned)f2bf(v.w * m) << 16);
    *reinterpret_cast<uint2*>(&Dlds[row * LSTR + c4 * 4]) = make_uint2(lo, hi);
  }
  for (int i = tid; i < (NNP - NN) * (NH / 4); i += 256) {  // zero pad rows 180..191
    int row = NN + (i >> 5), c4 = i & 31;
    *reinterpret_cast<uint2*>(&Dlds[row * LSTR + c4 * 4]) = make_uint2(0u, 0u);
  }
  __syncthreads();

  const int bl = lane & 15;   // fragment row(n)/col(m) within tile
  const int bg = lane >> 4;   // k-group / n-quarter

  #pragma unroll 1
  for (int g = 0; g < 2; ++g) {                 // 2 quads of queries per wave
    const int q0 = w * 8 + g * 4;

    // B operand fragments for the four queries of this quad (128 VGPR)
    short8 Qf[4][2][4];  // [qi][mt][ks]
    #pragma unroll
    for (int qi = 0; qi < 4; ++qi) {
      const unsigned short* Qp = Qb + (q0 + qi) * (NM * NH);
      #pragma unroll
      for (int mt = 0; mt < 2; ++mt)
        #pragma unroll
        for (int ks = 0; ks < 4; ++ks)
          Qf[qi][mt][ks] = *reinterpret_cast<const short8*>(
              Qp + (mt * 16 + bl) * NH + ks * 32 + bg * 8);
    }

    f32x4 run[4][2];  // [qi][mt]
    #pragma unroll
    for (int qi = 0; qi < 4; ++qi)
      #pragma unroll
      for (int mt = 0; mt < 2; ++mt)
        run[qi][mt] = (f32x4){NEG, NEG, NEG, NEG};

    #pragma unroll 2
    for (int nt = 0; nt < 12; ++nt) {
      short8 Da[4];
      #pragma unroll
      for (int ks = 0; ks < 4; ++ks)
        Da[ks] = *reinterpret_cast<const short8*>(
            &Dlds[(nt * 16 + bl) * LSTR + ks * 32 + bg * 8]);

      // 8 independent accumulator chains (4 qi x 2 mt)
      f32x4 acc[4][2];
      #pragma unroll
      for (int qi = 0; qi < 4; ++qi)
        #pragma unroll
        for (int mt = 0; mt < 2; ++mt)
          acc[qi][mt] = (f32x4){0.f, 0.f, 0.f, 0.f};

      #pragma unroll
      for (int ks = 0; ks < 4; ++ks)
        #pragma unroll
        for (int qi = 0; qi < 4; ++qi)
          #pragma unroll
          for (int mt = 0; mt < 2; ++mt)
            acc[qi][mt] = __builtin_amdgcn_mfma_f32_16x16x32_bf16(
                Da[ks], Qf[qi][mt][ks], acc[qi][mt], 0, 0, 0);

      // fold into running max; tile 11: rows n=176+bg*4+j, only bg==0 real
      const bool isTail = (nt == 11);
      #pragma unroll
      for (int qi = 0; qi < 4; ++qi)
        #pragma unroll
        for (int mt = 0; mt < 2; ++mt) {
          f32x4 v = acc[qi][mt];
          if (isTail) {
            #pragma unroll
            for (int j = 0; j < 4; ++j) v[j] = (bg == 0) ? v[j] : NEG;
          }
          run[qi][mt] = max4(run[qi][mt], v);
        }
    }

    // ---- in-loop reduction tails (4 qi, chains interleave) ----
    #pragma unroll
    for (int qi = 0; qi < 4; ++qi) {
      float a = fmaxf(fmaxf(run[qi][0][0], run[qi][0][1]),
                      fmaxf(run[qi][0][2], run[qi][0][3]));   // mt=0 (m = bl)
      float b = fmaxf(fmaxf(run[qi][1][0], run[qi][1][1]),
                      fmaxf(run[qi][1][2], run[qi][1][3]));   // mt=1 (m = bl+16)
      a = fmaxf(a, __shfl_xor(a, 16));
      a = fmaxf(a, __shfl_xor(a, 32));
      b = fmaxf(b, __shfl_xor(b, 16));
      b = fmaxf(b, __shfl_xor(b, 32));
      float s = a + b;                  // m = bl and m = bl+16
      s += __shfl_xor(s, 1);            // sum over the 16 bl classes
      s += __shfl_xor(s, 2);
      s += __shfl_xor(s, 4);
      s += __shfl_xor(s, 8);
      if (lane == 0) out[(q0 + qi) * ND + d] = s;
    }
  }
}

extern "C" void kernel_launch(void* const* d_in, const int* in_sizes, int n_in,
                              void* d_out, int out_size, void* d_ws, size_t ws_size,
                              hipStream_t stream) {
  const float* Q = (const float*)d_in[0];
  const float* D = (const float*)d_in[1];
  const int* qmask = (const int*)d_in[2];
  const int* dmask = (const int*)d_in[3];
  float* out = (float*)d_out;
  unsigned short* Qb = (unsigned short*)d_ws;  // 32*32*128 bf16 = 256 KB

  prep_q_kernel<<<(NQ * NM * NH / 4) / 256, 256, 0, stream>>>(Q, qmask, Qb);
  maxsim_kernel<<<ND, 256, 0, stream>>>(D, dmask, Qb, out);
}

// Round 8
// 42.235 us; speedup vs baseline: 1.2749x; 1.2749x over previous
//
#include <hip/hip_runtime.h>
#include <hip/hip_bf16.h>

typedef __attribute__((ext_vector_type(8))) short short8;
typedef __attribute__((ext_vector_type(4))) float f32x4;

#define NQ 32      // queries
#define NM 32      // query tokens
#define NH 128     // head dim
#define ND 512     // docs
#define NN 180     // doc tokens
#define NNP 192    // padded doc tokens (12 tiles of 16)
#define NT 12      // n-tiles
#define LSTR 136   // (fallback path) LDS row stride in shorts

#define QFRAG_BYTES (NQ * 2 * 4 * 64 * 16)            // 256 KB
#define DBLK_BYTES (NT * 4 * 64 * 16)                 // 49152 B per doc
#define DFRAG_BYTES (ND * DBLK_BYTES)                 // ~24 MB

static __device__ __forceinline__ unsigned short f2bf(float x) {
  __hip_bfloat16 h = __float2bfloat16(x);
  return __builtin_bit_cast(unsigned short, h);
}

static __device__ __forceinline__ f32x4 max4(f32x4 a, f32x4 b) {
  f32x4 r;
  r[0] = fmaxf(a[0], b[0]); r[1] = fmaxf(a[1], b[1]);
  r[2] = fmaxf(a[2], b[2]); r[3] = fmaxf(a[3], b[3]);
  return r;
}

static __device__ __forceinline__ uint4 pack8(const float* v, float m) {
  unsigned int a = (unsigned)f2bf(v[0] * m) | ((unsigned)f2bf(v[1] * m) << 16);
  unsigned int b = (unsigned)f2bf(v[2] * m) | ((unsigned)f2bf(v[3] * m) << 16);
  unsigned int c = (unsigned)f2bf(v[4] * m) | ((unsigned)f2bf(v[5] * m) << 16);
  unsigned int e = (unsigned)f2bf(v[6] * m) | ((unsigned)f2bf(v[7] * m) << 16);
  return make_uint4(a, b, c, e);
}

// ===================== fragment-layout prep =====================
// Fragment element (lane, j) of tile (x, ks) = M[x*16 + (lane&15)][ks*32 + (lane>>4)*8 + j]
// -> stored at frag_base*1024 + lane*16. MFMA consumes it directly; LDS reads at
// base + lane*16 are conflict-free; prep does ALL masking + bf16 conversion once.

// Qb_frag[q][mt][ks][lane][8]
__global__ __launch_bounds__(256) void prep_q_frag(
    const float* __restrict__ Q, const int* __restrict__ qmask,
    unsigned short* __restrict__ Qb) {
  int idx = blockIdx.x * 256 + threadIdx.x;   // 16384 fragment-lanes
  int lane = idx & 63;
  int ks = (idx >> 6) & 3;
  int mt = (idx >> 8) & 1;
  int q  = idx >> 9;
  int row = mt * 16 + (lane & 15);
  int k0  = ks * 32 + (lane >> 4) * 8;
  const float* src = Q + (q * NM + row) * NH + k0;
  float v[8];
  *reinterpret_cast<float4*>(&v[0]) = *reinterpret_cast<const float4*>(src);
  *reinterpret_cast<float4*>(&v[4]) = *reinterpret_cast<const float4*>(src + 4);
  float m = (float)qmask[q * NM + row];
  reinterpret_cast<uint4*>(Qb)[idx] = pack8(v, m);
}

// Db_frag[d][nt][ks][lane][8]; pad rows (n>=180) written as zeros (masked at fold)
__global__ __launch_bounds__(256) void prep_d_frag(
    const float* __restrict__ D, const int* __restrict__ dmask,
    unsigned short* __restrict__ Db) {
  int idx = blockIdx.x * 256 + threadIdx.x;   // 1,572,864 fragment-lanes
  int lane = idx & 63;
  int ks = (idx >> 6) & 3;
  int r  = idx >> 8;          // d*NT + nt
  int nt = r % NT;
  int d  = r / NT;
  int row = nt * 16 + (lane & 15);
  int k0  = ks * 32 + (lane >> 4) * 8;
  uint4 outv = make_uint4(0u, 0u, 0u, 0u);
  if (row < NN) {
    const float* src = D + (d * NN + row) * NH + k0;
    float v[8];
    *reinterpret_cast<float4*>(&v[0]) = *reinterpret_cast<const float4*>(src);
    *reinterpret_cast<float4*>(&v[4]) = *reinterpret_cast<const float4*>(src + 4);
    float m = (float)dmask[d * NN + row];
    outv = pack8(v, m);
  }
  reinterpret_cast<uint4*>(Db)[idx] = outv;
}

// ===================== maxsim (fragment path) =====================
// 1024 blocks x 512 threads (8 waves). Block = (doc, half); XCD-swizzled so both
// halves of a doc land on the same XCD L2. Each wave owns ONE query pair
// (~125 VGPR -> 4 waves/SIMD; the occupancy lever). LDS = verbatim Db_frag[d]
// copy (linear 16B/lane stage, conflict-free lane*16 ds_read_b128).
// Prep pass already did masking+conversion: zero staging VALU here.
__global__ __launch_bounds__(512) void maxsim_frag(
    const unsigned short* __restrict__ Db, const unsigned short* __restrict__ Qb,
    float* __restrict__ out) {
  __shared__ unsigned char Dlds[DBLK_BYTES];  // 49152 B
  const int bid = blockIdx.x;
  const int d    = ((bid >> 4) << 3) | (bid & 7);   // same XCD for both halves
  const int half = (bid >> 3) & 1;
  const int tid = threadIdx.x;
  const int lane = tid & 63;
  const int w = tid >> 6;
  const int bg = lane >> 4;
  const float NEG = -__builtin_inff();

  // ---- stage Db[d] -> LDS verbatim (6 x 16B per thread, conflict-free) ----
  {
    const uint4* gsrc = reinterpret_cast<const uint4*>(
        reinterpret_cast<const char*>(Db) + d * DBLK_BYTES);
    uint4* ldst = reinterpret_cast<uint4*>(&Dlds[0]);
    #pragma unroll
    for (int i = 0; i < DBLK_BYTES / (512 * 16); ++i)
      ldst[i * 512 + tid] = gsrc[i * 512 + tid];
  }
  __syncthreads();

  // ---- this wave's query pair ----
  const int q0 = (half * 8 + w) * 2;

  short8 Qf[2][2][4];  // [qi][mt][ks] = 64 VGPR
  #pragma unroll
  for (int qi = 0; qi < 2; ++qi)
    #pragma unroll
    for (int mt = 0; mt < 2; ++mt)
      #pragma unroll
      for (int ks = 0; ks < 4; ++ks)
        Qf[qi][mt][ks] = *reinterpret_cast<const short8*>(
            reinterpret_cast<const char*>(Qb) +
            ((((q0 + qi) * 2 + mt) * 4 + ks) << 10) + (lane << 4));

  f32x4 run[2][2];
  #pragma unroll
  for (int qi = 0; qi < 2; ++qi)
    #pragma unroll
    for (int mt = 0; mt < 2; ++mt)
      run[qi][mt] = (f32x4){NEG, NEG, NEG, NEG};

  #pragma unroll 2
  for (int nt = 0; nt < NT; ++nt) {
    short8 Da[4];
    #pragma unroll
    for (int ks = 0; ks < 4; ++ks)
      Da[ks] = *reinterpret_cast<const short8*>(
          &Dlds[((nt * 4 + ks) << 10) + (lane << 4)]);

    f32x4 acc[2][2];
    #pragma unroll
    for (int qi = 0; qi < 2; ++qi)
      #pragma unroll
      for (int mt = 0; mt < 2; ++mt)
        acc[qi][mt] = (f32x4){0.f, 0.f, 0.f, 0.f};

    #pragma unroll
    for (int ks = 0; ks < 4; ++ks)
      #pragma unroll
      for (int qi = 0; qi < 2; ++qi)
        #pragma unroll
        for (int mt = 0; mt < 2; ++mt)
          acc[qi][mt] = __builtin_amdgcn_mfma_f32_16x16x32_bf16(
              Da[ks], Qf[qi][mt][ks], acc[qi][mt], 0, 0, 0);

    // tile 11: rows n=176+bg*4+j; only bg==0 (176..179) real; pads are zeros -> mask to -inf
    const bool isTail = (nt == NT - 1);
    #pragma unroll
    for (int qi = 0; qi < 2; ++qi)
      #pragma unroll
      for (int mt = 0; mt < 2; ++mt) {
        f32x4 v = acc[qi][mt];
        if (isTail) {
          #pragma unroll
          for (int j = 0; j < 4; ++j) v[j] = (bg == 0) ? v[j] : NEG;
        }
        run[qi][mt] = max4(run[qi][mt], v);
      }
  }

  // ---- reduction: j-fold, xor16/32 max over n, xor1..8 sum over m ----
  #pragma unroll
  for (int qi = 0; qi < 2; ++qi) {
    float a = fmaxf(fmaxf(run[qi][0][0], run[qi][0][1]),
                    fmaxf(run[qi][0][2], run[qi][0][3]));   // m = lane&15
    float b = fmaxf(fmaxf(run[qi][1][0], run[qi][1][1]),
                    fmaxf(run[qi][1][2], run[qi][1][3]));   // m = (lane&15)+16
    a = fmaxf(a, __shfl_xor(a, 16));
    a = fmaxf(a, __shfl_xor(a, 32));
    b = fmaxf(b, __shfl_xor(b, 16));
    b = fmaxf(b, __shfl_xor(b, 32));
    float s = a + b;
    s += __shfl_xor(s, 1);
    s += __shfl_xor(s, 2);
    s += __shfl_xor(s, 4);
    s += __shfl_xor(s, 8);
    if (lane == 0) out[(q0 + qi) * ND + d] = s;
  }
}

// ===================== fallback path (R6, proven 50 us) =====================
__global__ __launch_bounds__(256, 1) void prep_q_rows(
    const float* __restrict__ Q, const int* __restrict__ qmask,
    unsigned short* __restrict__ Qb) {
  int idx = blockIdx.x * 256 + threadIdx.x;
  int row = idx >> 5;
  float m = (float)qmask[row];
  float4 v = reinterpret_cast<const float4*>(Q)[idx];
  unsigned int lo = (unsigned)f2bf(v.x * m) | ((unsigned)f2bf(v.y * m) << 16);
  unsigned int hi = (unsigned)f2bf(v.z * m) | ((unsigned)f2bf(v.w * m) << 16);
  reinterpret_cast<uint2*>(Qb)[idx] = make_uint2(lo, hi);
}

__global__ __launch_bounds__(256) void maxsim_fallback(
    const float* __restrict__ D, const int* __restrict__ dmask,
    const unsigned short* __restrict__ Qb, float* __restrict__ out) {
  __shared__ unsigned short Dlds[NNP * LSTR];
  const int d = blockIdx.x;
  const int tid = threadIdx.x;
  const int lane = tid & 63;
  const int w = tid >> 6;
  const float NEG = -__builtin_inff();

  const float4* Dsrc = reinterpret_cast<const float4*>(D) + d * (NN * NH / 4);
  for (int i = tid; i < NN * (NH / 4); i += 256) {
    int row = i >> 5, c4 = i & 31;
    float m = (float)dmask[d * NN + row];
    float4 v = Dsrc[i];
    unsigned int lo = (unsigned)f2bf(v.x * m) | ((unsigned)f2bf(v.y * m) << 16);
    unsigned int hi = (unsigned)f2bf(v.z * m) | ((unsigned)f2bf(v.w * m) << 16);
    *reinterpret_cast<uint2*>(&Dlds[row * LSTR + c4 * 4]) = make_uint2(lo, hi);
  }
  for (int i = tid; i < (NNP - NN) * (NH / 4); i += 256) {
    int row = NN + (i >> 5), c4 = i & 31;
    *reinterpret_cast<uint2*>(&Dlds[row * LSTR + c4 * 4]) = make_uint2(0u, 0u);
  }
  __syncthreads();

  const int bl = lane & 15;
  const int bg = lane >> 4;

  #pragma unroll 1
  for (int p = 0; p < 4; ++p) {
    const int q0 = w * 8 + p * 2;
    const unsigned short* Qp0 = Qb + (q0 + 0) * (NM * NH);
    const unsigned short* Qp1 = Qb + (q0 + 1) * (NM * NH);
    short8 Qf[2][2][4];
    #pragma unroll
    for (int mt = 0; mt < 2; ++mt)
      #pragma unroll
      for (int ks = 0; ks < 4; ++ks) {
        Qf[0][mt][ks] = *reinterpret_cast<const short8*>(Qp0 + (mt * 16 + bl) * NH + ks * 32 + bg * 8);
        Qf[1][mt][ks] = *reinterpret_cast<const short8*>(Qp1 + (mt * 16 + bl) * NH + ks * 32 + bg * 8);
      }
    f32x4 run[2][2];
    #pragma unroll
    for (int qi = 0; qi < 2; ++qi)
      #pragma unroll
      for (int mt = 0; mt < 2; ++mt) run[qi][mt] = (f32x4){NEG, NEG, NEG, NEG};

    #pragma unroll
    for (int ntp = 0; ntp < 6; ++ntp) {
      short8 Da[2][4];
      #pragma unroll
      for (int nti = 0; nti < 2; ++nti)
        #pragma unroll
        for (int ks = 0; ks < 4; ++ks)
          Da[nti][ks] = *reinterpret_cast<const short8*>(
              &Dlds[((ntp * 2 + nti) * 16 + bl) * LSTR + ks * 32 + bg * 8]);
      f32x4 acc[2][2][2];
      #pragma unroll
      for (int nti = 0; nti < 2; ++nti)
        #pragma unroll
        for (int qi = 0; qi < 2; ++qi)
          #pragma unroll
          for (int mt = 0; mt < 2; ++mt) acc[nti][qi][mt] = (f32x4){0.f, 0.f, 0.f, 0.f};
      #pragma unroll
      for (int ks = 0; ks < 4; ++ks)
        #pragma unroll
        for (int nti = 0; nti < 2; ++nti)
          #pragma unroll
          for (int qi = 0; qi < 2; ++qi)
            #pragma unroll
            for (int mt = 0; mt < 2; ++mt)
              acc[nti][qi][mt] = __builtin_amdgcn_mfma_f32_16x16x32_bf16(
                  Da[nti][ks], Qf[qi][mt][ks], acc[nti][qi][mt], 0, 0, 0);
      #pragma unroll
      for (int nti = 0; nti < 2; ++nti) {
        const bool isTail = (ntp == 5) && (nti == 1);
        #pragma unroll
        for (int qi = 0; qi < 2; ++qi)
          #pragma unroll
          for (int mt = 0; mt < 2; ++mt) {
            f32x4 v = acc[nti][qi][mt];
            if (isTail) {
              #pragma unroll
              for (int j = 0; j < 4; ++j) v[j] = (bg == 0) ? v[j] : NEG;
            }
            run[qi][mt] = max4(run[qi][mt], v);
          }
      }
    }
    #pragma unroll
    for (int qi = 0; qi < 2; ++qi) {
      float a = fmaxf(fmaxf(run[qi][0][0], run[qi][0][1]), fmaxf(run[qi][0][2], run[qi][0][3]));
      float b = fmaxf(fmaxf(run[qi][1][0], run[qi][1][1]), fmaxf(run[qi][1][2], run[qi][1][3]));
      a = fmaxf(a, __shfl_xor(a, 16));
      a = fmaxf(a, __shfl_xor(a, 32));
      b = fmaxf(b, __shfl_xor(b, 16));
      b = fmaxf(b, __shfl_xor(b, 32));
      float s = a + b;
      s += __shfl_xor(s, 1);
      s += __shfl_xor(s, 2);
      s += __shfl_xor(s, 4);
      s += __shfl_xor(s, 8);
      if (lane == 0) out[(q0 + qi) * ND + d] = s;
    }
  }
}

extern "C" void kernel_launch(void* const* d_in, const int* in_sizes, int n_in,
                              void* d_out, int out_size, void* d_ws, size_t ws_size,
                              hipStream_t stream) {
  const float* Q = (const float*)d_in[0];
  const float* D = (const float*)d_in[1];
  const int* qmask = (const int*)d_in[2];
  const int* dmask = (const int*)d_in[3];
  float* out = (float*)d_out;

  if (ws_size >= (size_t)(QFRAG_BYTES + DFRAG_BYTES)) {
    unsigned short* Qb = (unsigned short*)d_ws;                          // 256 KB
    unsigned short* Db = (unsigned short*)((char*)d_ws + QFRAG_BYTES);   // ~24 MB
    prep_q_frag<<<16384 / 256, 256, 0, stream>>>(Q, qmask, Qb);
    prep_d_frag<<<(ND * NT * 4 * 64) / 256, 256, 0, stream>>>(D, dmask, Db);
    maxsim_frag<<<ND * 2, 512, 0, stream>>>(Db, Qb, out);
  } else {
    unsigned short* Qb = (unsigned short*)d_ws;                          // 256 KB
    prep_q_rows<<<(NQ * NM * NH / 4) / 256, 256, 0, stream>>>(Q, qmask, Qb);
    maxsim_fallback<<<ND, 256, 0, stream>>>(D, dmask, Qb, out);
  }
}

// Round 9
// 34.756 us; speedup vs baseline: 1.5492x; 1.2152x over previous
//
#include <hip/hip_runtime.h>
#include <hip/hip_bf16.h>

typedef __attribute__((ext_vector_type(8))) short short8;
typedef __attribute__((ext_vector_type(4))) float f32x4;

#define NQ 32      // queries
#define NM 32      // query tokens
#define NH 128     // head dim
#define ND 512     // docs
#define NN 180     // doc tokens
#define NNP 192    // padded doc tokens (12 tiles of 16)
#define NT 12      // n-tiles
#define LSTR 136   // LDS row stride in shorts (272 B; b128 frag reads are minimal-conflict)

#define QFRAG_BYTES (NQ * 2 * 4 * 64 * 16)   // 256 KB

static __device__ __forceinline__ unsigned short f2bf(float x) {
  __hip_bfloat16 h = __float2bfloat16(x);
  return __builtin_bit_cast(unsigned short, h);
}

static __device__ __forceinline__ uint4 pack8(const float* v, float m) {
  unsigned int a = (unsigned)f2bf(v[0] * m) | ((unsigned)f2bf(v[1] * m) << 16);
  unsigned int b = (unsigned)f2bf(v[2] * m) | ((unsigned)f2bf(v[3] * m) << 16);
  unsigned int c = (unsigned)f2bf(v[4] * m) | ((unsigned)f2bf(v[5] * m) << 16);
  unsigned int e = (unsigned)f2bf(v[6] * m) | ((unsigned)f2bf(v[7] * m) << 16);
  return make_uint4(a, b, c, e);
}

// Qb_frag[q][mt][ks][lane][8]: fragment element (lane,j) = Qm[q][mt*16+(lane&15)][ks*32+(lane>>4)*8+j]
// MFMA-ready; maxsim loads it as one coalesced 16B/lane burst per fragment.
__global__ __launch_bounds__(256) void prep_q_frag(
    const float* __restrict__ Q, const int* __restrict__ qmask,
    unsigned short* __restrict__ Qb) {
  int idx = blockIdx.x * 256 + threadIdx.x;   // 16384 fragment-lanes
  int lane = idx & 63;
  int ks = (idx >> 6) & 3;
  int mt = (idx >> 8) & 1;
  int q  = idx >> 9;
  int row = mt * 16 + (lane & 15);
  int k0  = ks * 32 + (lane >> 4) * 8;
  const float* src = Q + (q * NM + row) * NH + k0;
  float v[8];
  *reinterpret_cast<float4*>(&v[0]) = *reinterpret_cast<const float4*>(src);
  *reinterpret_cast<float4*>(&v[4]) = *reinterpret_cast<const float4*>(src + 4);
  float m = (float)qmask[q * NM + row];
  reinterpret_cast<uint4*>(Qb)[idx] = pack8(v, m);
}

// 1024 blocks x 512 threads (8 waves). Block = (doc, half), XCD-paired via
// d = ((bid>>4)<<3)|(bid&7) so both halves of a doc land on the same XCD's L2
// (D fetched from HBM once). Each wave owns ONE query pair, fully unrolled:
// Qf 64 + Da 16 + acc 16 + scalar run 4 + addr ~ 126 VGPR <= 128, pinned by
// __launch_bounds__(512,4) -> 2 blocks/CU (LDS 2x51KB) = 4 waves/SIMD (the
// occupancy lever: every prior round ran 2 waves/SIMD and was latency-bound).
// Operands swapped: C[n,m] = mfma(Dfrag, Qfrag); max-over-n = j-fold + xor16/32.
__global__ __launch_bounds__(512, 4) void maxsim_kernel(
    const float* __restrict__ D, const int* __restrict__ dmask,
    const unsigned short* __restrict__ Qb, float* __restrict__ out) {
  __shared__ unsigned short Dlds[NNP * LSTR];  // 52224 B
  const int bid = blockIdx.x;
  const int d    = ((bid >> 4) << 3) | (bid & 7);
  const int half = (bid >> 3) & 1;
  const int tid = threadIdx.x;
  const int lane = tid & 63;
  const int w = tid >> 6;
  const float NEG = -__builtin_inff();

  // ---- stage masked D -> LDS bf16 (row-major, coalesced float4 reads) ----
  const float4* Dsrc = reinterpret_cast<const float4*>(D) + d * (NN * NH / 4);
  const int* dmrow = dmask + d * NN;
  for (int i = tid; i < NN * (NH / 4); i += 512) {
    int row = i >> 5, c4 = i & 31;
    float m = (float)dmrow[row];
    float4 v = Dsrc[i];
    unsigned int lo = (unsigned)f2bf(v.x * m) | ((unsigned)f2bf(v.y * m) << 16);
    unsigned int hi = (unsigned)f2bf(v.z * m) | ((unsigned)f2bf(v.w * m) << 16);
    *reinterpret_cast<uint2*>(&Dlds[row * LSTR + c4 * 4]) = make_uint2(lo, hi);
  }
  for (int i = tid; i < (NNP - NN) * (NH / 4); i += 512) {  // zero pad rows 180..191
    int row = NN + (i >> 5), c4 = i & 31;
    *reinterpret_cast<uint2*>(&Dlds[row * LSTR + c4 * 4]) = make_uint2(0u, 0u);
  }
  __syncthreads();

  const int bl = lane & 15;   // fragment row(n)/col(m) within tile
  const int bg = lane >> 4;   // k-group / n-quarter

  // ---- this wave's query pair: B fragments from frag-ordered Qb (64 VGPR) ----
  const int q0 = (half * 8 + w) * 2;
  short8 Qf[2][2][4];  // [qi][mt][ks]
  #pragma unroll
  for (int qi = 0; qi < 2; ++qi)
    #pragma unroll
    for (int mt = 0; mt < 2; ++mt)
      #pragma unroll
      for (int ks = 0; ks < 4; ++ks)
        Qf[qi][mt][ks] = *reinterpret_cast<const short8*>(
            reinterpret_cast<const char*>(Qb) +
            ((((q0 + qi) * 2 + mt) * 4 + ks) << 10) + (lane << 4));

  float run[2][2];     // scalar running max per (qi, mt)
  #pragma unroll
  for (int qi = 0; qi < 2; ++qi)
    #pragma unroll
    for (int mt = 0; mt < 2; ++mt) run[qi][mt] = NEG;

  #pragma unroll 2
  for (int nt = 0; nt < NT; ++nt) {
    short8 Da[4];
    #pragma unroll
    for (int ks = 0; ks < 4; ++ks)
      Da[ks] = *reinterpret_cast<const short8*>(
          &Dlds[(nt * 16 + bl) * LSTR + ks * 32 + bg * 8]);

    f32x4 acc[2][2];   // 4 independent MFMA chains
    #pragma unroll
    for (int qi = 0; qi < 2; ++qi)
      #pragma unroll
      for (int mt = 0; mt < 2; ++mt) acc[qi][mt] = (f32x4){0.f, 0.f, 0.f, 0.f};

    #pragma unroll
    for (int ks = 0; ks < 4; ++ks)
      #pragma unroll
      for (int qi = 0; qi < 2; ++qi)
        #pragma unroll
        for (int mt = 0; mt < 2; ++mt)
          acc[qi][mt] = __builtin_amdgcn_mfma_f32_16x16x32_bf16(
              Da[ks], Qf[qi][mt][ks], acc[qi][mt], 0, 0, 0);

    // j-fold then into scalar run; tile 11: rows n=176+bg*4+j, only bg==0 real
    const bool isTail = (nt == NT - 1);
    #pragma unroll
    for (int qi = 0; qi < 2; ++qi)
      #pragma unroll
      for (int mt = 0; mt < 2; ++mt) {
        float v = fmaxf(fmaxf(acc[qi][mt][0], acc[qi][mt][1]),
                        fmaxf(acc[qi][mt][2], acc[qi][mt][3]));
        if (isTail && bg != 0) v = NEG;
        run[qi][mt] = fmaxf(run[qi][mt], v);
      }
  }

  // ---- reduction: xor16/32 max over n-quarters, xor1..8 sum over m ----
  #pragma unroll
  for (int qi = 0; qi < 2; ++qi) {
    float a = run[qi][0];   // m = lane&15
    float b = run[qi][1];   // m = (lane&15)+16
    a = fmaxf(a, __shfl_xor(a, 16));
    a = fmaxf(a, __shfl_xor(a, 32));
    b = fmaxf(b, __shfl_xor(b, 16));
    b = fmaxf(b, __shfl_xor(b, 32));
    float s = a + b;
    s += __shfl_xor(s, 1);
    s += __shfl_xor(s, 2);
    s += __shfl_xor(s, 4);
    s += __shfl_xor(s, 8);
    if (lane == 0) out[(q0 + qi) * ND + d] = s;
  }
}

extern "C" void kernel_launch(void* const* d_in, const int* in_sizes, int n_in,
                              void* d_out, int out_size, void* d_ws, size_t ws_size,
                              hipStream_t stream) {
  const float* Q = (const float*)d_in[0];
  const float* D = (const float*)d_in[1];
  const int* qmask = (const int*)d_in[2];
  const int* dmask = (const int*)d_in[3];
  float* out = (float*)d_out;
  unsigned short* Qb = (unsigned short*)d_ws;  // 256 KB frag-ordered Q

  prep_q_frag<<<16384 / 256, 256, 0, stream>>>(Q, qmask, Qb);
  maxsim_kernel<<<ND * 2, 512, 0, stream>>>(D, dmask, Qb, out);
}